// Round 6
// baseline (207.047 us; speedup 1.0000x reference)
//
#include <hip/hip_runtime.h>

// MultiHeadSelfAttention: B=2, N=2048, D=768, H=12, DH=64, scale=1/8.
// d_in / d_out are FP32; grading is bf16-leniency (2% of absmax).
// R6: attn64 -> 32 q-rows/wave (amortize K/V LDS frag reads, the measured
//     bottleneck); QKV-gemm V^T epilogue via LDS transpose (coalesced b128
//     stores, was 2-B scatter); Q pre-scaled by log2(e)/8 in GEMM epilogue.

#define CB 2
#define CN 2048
#define CD 768
#define CH 12
#define CDH 64
// exp(s/8) = exp2(s * 0.125 * log2(e)) ; folded into Q at QKV epilogue
#define CEXPSCALE 0.18033688f

typedef __bf16 bf16x8 __attribute__((ext_vector_type(8)));
typedef float f32x4 __attribute__((ext_vector_type(4)));
typedef unsigned short u16x8 __attribute__((ext_vector_type(8)));

static __device__ __forceinline__ unsigned short f2bf(float f) {
  union { float f; unsigned u; } v; v.f = f;
  unsigned r = v.u + 0x7fffu + ((v.u >> 16) & 1u);  // RNE
  return (unsigned short)(r >> 16);
}

// async global->LDS, 16B per lane; LDS dest = wave-uniform base + lane*16
static __device__ __forceinline__ void gld_lds16(const unsigned short* g, unsigned short* lds_base) {
  __builtin_amdgcn_global_load_lds(
      (const __attribute__((address_space(1))) unsigned int*)g,
      (__attribute__((address_space(3))) unsigned int*)(unsigned int)(unsigned long long)lds_base,
      16, 0, 0);
}

// ---------------- x: fp32 -> bf16, 8 elems/thread ----------------
__global__ __launch_bounds__(256) void cvt8(const float* __restrict__ src,
                                            unsigned short* __restrict__ dst) {
  size_t i = ((size_t)blockIdx.x * 256 + threadIdx.x) * 8;
  f32x4 a = *(const f32x4*)&src[i];
  f32x4 b = *(const f32x4*)&src[i + 4];
  u16x8 o;
#pragma unroll
  for (int j = 0; j < 4; ++j) { o[j] = f2bf(a[j]); o[4 + j] = f2bf(b[j]); }
  *(u16x8*)&dst[i] = o;
}

// ---------------- weight: fp32 R x C -> bf16 C x R (transposed) ----------------
__global__ __launch_bounds__(256) void transpose_cvt(const float* __restrict__ src,
                                                     unsigned short* __restrict__ dst,
                                                     int R, int C) {
  __shared__ __align__(16) unsigned short t[64][72];
  const int c0 = blockIdx.x * 64, r0 = blockIdx.y * 64;
  const int tid = threadIdx.x;
#pragma unroll
  for (int i = 0; i < 4; ++i) {
    int c = tid + i * 256;
    int row = c >> 4, cc = (c & 15) * 4;
    f32x4 v = *(const f32x4*)&src[(size_t)(r0 + row) * C + c0 + cc];
#pragma unroll
    for (int j = 0; j < 4; ++j) t[row][cc + j] = f2bf(v[j]);
  }
  __syncthreads();
#pragma unroll
  for (int i = 0; i < 2; ++i) {
    int c = tid + i * 256;
    int drow = c >> 3, rc = (c & 7) * 8;
    u16x8 v;
#pragma unroll
    for (int j = 0; j < 8; ++j) v[j] = t[rc + j][drow];
    *(u16x8*)&dst[(size_t)(c0 + drow) * R + r0 + rc] = v;
  }
}

// ---------------- GEMM: C[M,N] = A[M,K] @ Bt[N,K]^T + bias[N] ----------------
// Dynamic LDS: As(4096) | Bs(4096) elems; Ct (128x136) OVERLAYS As/Bs for the
// mode-0 V-block transposed epilogue (safe: after final k-loop barrier).
// mode 0: col0<768 -> Q scatter (pre-scaled by CEXPSCALE); col0<1536 -> K
//         scatter; col0>=1536 -> V^T via LDS transpose, coalesced b128 stores.
// mode 1: fp32 row-major store.
extern __shared__ __align__(16) unsigned short smem[];
__global__ __launch_bounds__(256) void gemm128(const unsigned short* __restrict__ A,
                                               const unsigned short* __restrict__ Bt,
                                               const float* __restrict__ bias,
                                               int M, int N, int K, int mode,
                                               unsigned short* __restrict__ o0,
                                               unsigned short* __restrict__ o1,
                                               unsigned short* __restrict__ o2,
                                               float* __restrict__ outF) {
  unsigned short* As = smem;
  unsigned short* Bs = smem + 128 * 32;
  unsigned short* Ct = smem;  // 128 x 136, overlays As/Bs in epilogue
  const int tid = threadIdx.x;
  const int w = tid >> 6, lane = tid & 63, quad = lane >> 4, lc = lane & 15;
  const int wm = (w >> 1) * 64, wn = (w & 1) * 64;
  const int row0 = blockIdx.y * 128, col0 = blockIdx.x * 128;
  f32x4 acc[4][4] = {};

  const int rl = lane >> 2, cl = lane & 3;
  const int gc = cl ^ ((rl >> 1) & 3);
  const int rsw = (lc >> 1) & 3;

  for (int k0 = 0; k0 < K; k0 += 32) {
#pragma unroll
    for (int j = 0; j < 2; ++j) {
      int r = w * 32 + j * 16 + rl;
      gld_lds16(&A[(size_t)(row0 + r) * K + k0 + gc * 8], &As[(w * 32 + j * 16) * 32]);
      gld_lds16(&Bt[(size_t)(col0 + r) * K + k0 + gc * 8], &Bs[(w * 32 + j * 16) * 32]);
    }
    __syncthreads();
    bf16x8 af[4], bfv[4];
#pragma unroll
    for (int mt = 0; mt < 4; ++mt)
      af[mt] = *(const bf16x8*)&As[(wm + mt * 16 + lc) * 32 + (quad ^ rsw) * 8];
#pragma unroll
    for (int nt = 0; nt < 4; ++nt)
      bfv[nt] = *(const bf16x8*)&Bs[(wn + nt * 16 + lc) * 32 + (quad ^ rsw) * 8];
#pragma unroll
    for (int mt = 0; mt < 4; ++mt)
#pragma unroll
      for (int nt = 0; nt < 4; ++nt)
        acc[mt][nt] = __builtin_amdgcn_mfma_f32_16x16x32_bf16(af[mt], bfv[nt], acc[mt][nt], 0, 0, 0);
    __syncthreads();
  }

  if (mode == 0 && col0 >= 1536) {
    // -------- V block: transpose through LDS, store V^T coalesced --------
#pragma unroll
    for (int mt = 0; mt < 4; ++mt) {
#pragma unroll
      for (int nt = 0; nt < 4; ++nt) {
        int jl = wn + nt * 16 + lc;            // V-dim (0..127)
        int il0 = wm + mt * 16 + quad * 4;     // token-dim (0..127), 4 consecutive
        unsigned short a0 = f2bf(acc[mt][nt][0] + bias[col0 + jl]);
        unsigned short a1 = f2bf(acc[mt][nt][1] + bias[col0 + jl]);
        unsigned short a2 = f2bf(acc[mt][nt][2] + bias[col0 + jl]);
        unsigned short a3 = f2bf(acc[mt][nt][3] + bias[col0 + jl]);
        uint2 dd;
        dd.x = (unsigned)a0 | ((unsigned)a1 << 16);
        dd.y = (unsigned)a2 | ((unsigned)a3 << 16);
        *(uint2*)&Ct[jl * 136 + il0] = dd;
      }
    }
    __syncthreads();
    const int b = row0 >> 11, n0 = row0 & 2047;
#pragma unroll
    for (int i = 0; i < 8; ++i) {
      int c = tid + i * 256;                   // 2048 chunks: 128 rows x 16
      int jl = c >> 4, cc = (c & 15) * 8;
      u16x8 v = *(const u16x8*)&Ct[jl * 136 + cc];
      int jcol = col0 - 1536 + jl;             // 0..767
      int h = jcol >> 6, d = jcol & 63;
      size_t gr = ((size_t)(b * CH + h) * CDH + d);
      *(u16x8*)&o2[gr * CN + n0 + cc] = v;
    }
  } else {
    // epilogue: C/D layout col=lane&15, row=quad*4+reg
#pragma unroll
    for (int mt = 0; mt < 4; ++mt) {
#pragma unroll
      for (int nt = 0; nt < 4; ++nt) {
#pragma unroll
        for (int r = 0; r < 4; ++r) {
          int i = row0 + wm + mt * 16 + quad * 4 + r;
          int j = col0 + wn + nt * 16 + lc;
          float v = acc[mt][nt][r] + bias[j];
          if (mode == 0) {
            int b = i >> 11, n = i & 2047;
            int sec = j >> 9 >= 3 ? (j >= 1536 ? 2 : 1) : (j >= 768 ? 1 : 0);
            sec = (j >= 1536) ? 2 : (j >= 768 ? 1 : 0);
            int within = j - sec * 768;
            int h = within >> 6, d = within & 63;
            int bh = b * CH + h;
            if (sec == 0)      o0[((size_t)bh * CN + n) * CDH + d] = f2bf(v * CEXPSCALE);
            else               o1[((size_t)bh * CN + n) * CDH + d] = f2bf(v);
          } else {
            outF[(size_t)i * N + j] = v;
          }
        }
      }
    }
  }
}

// ---------------- flash attention, LDS-staged K/V, no-max softmax ----------------
// grid (B*H, N/128): bh pinned to one XCD (24%8==0). 4 waves x 32 q-rows each
// (2 subtiles of 16): K/V LDS fragment reads amortized over 2x MFMA/exp work.
// Q arrives PRE-SCALED by log2(e)/8 -> p = exp2(z) directly.
__global__ __launch_bounds__(256, 3) void attn64(const unsigned short* __restrict__ Q,
                                                 const unsigned short* __restrict__ K,
                                                 const unsigned short* __restrict__ Vt,
                                                 unsigned short* __restrict__ O) {
  __shared__ __align__(16) unsigned short Kls[2][64 * 64];
  __shared__ __align__(16) unsigned short Vls[2][64 * 64];
  __shared__ __align__(16) unsigned short P[4][2][16 * 72];  // wave x subtile x 16q x 64keys(+8)
  const int bh = blockIdx.x, qt = blockIdx.y;
  const int tid = threadIdx.x;
  const int w = tid >> 6, lane = tid & 63, quad = lane >> 4, lc = lane & 15;
  const unsigned short* Qb = Q + (size_t)bh * CN * CDH;
  const unsigned short* Kb = K + (size_t)bh * CN * CDH;
  const unsigned short* Vb = Vt + (size_t)bh * CDH * CN;
  const int q0 = qt * 128 + w * 32;

  const int sr = lane >> 3, sc = lane & 7;
  const int sg = sc ^ sr;
  const int ksw = lc & 7;
  const int c0r = quad ^ ksw;
  const int c1r = c0r ^ 4;

  bf16x8 qf[2][2];
#pragma unroll
  for (int s = 0; s < 2; ++s) {
    qf[s][0] = *(const bf16x8*)&Qb[(size_t)(q0 + s * 16 + lc) * CDH + quad * 8];
    qf[s][1] = *(const bf16x8*)&Qb[(size_t)(q0 + s * 16 + lc) * CDH + 32 + quad * 8];
  }

  f32x4 o[2][4] = {};
  float rs[2] = {0.f, 0.f};

  // prologue: stage tile 0 into buffer 0 (wave w stages rows [16w,16w+16))
#pragma unroll
  for (int j2 = 0; j2 < 2; ++j2) {
    int j = w * 2 + j2;
    int r = j * 8 + sr;
    gld_lds16(&Kb[(size_t)r * CDH + sg * 8], &Kls[0][j * 8 * 64]);
    gld_lds16(&Vb[(size_t)r * CN + 0 + sg * 8], &Vls[0][j * 8 * 64]);
  }

  for (int kt = 0; kt < CN / 64; ++kt) {
    const int bb = kt & 1;
    __syncthreads();  // tile kt staged
    if (kt + 1 < CN / 64) {
      const int kn = (kt + 1) * 64;
#pragma unroll
      for (int j2 = 0; j2 < 2; ++j2) {
        int j = w * 2 + j2;
        int r = j * 8 + sr;
        gld_lds16(&Kb[(size_t)(kn + r) * CDH + sg * 8], &Kls[bb ^ 1][j * 8 * 64]);
        gld_lds16(&Vb[(size_t)r * CN + kn + sg * 8], &Vls[bb ^ 1][j * 8 * 64]);
      }
    }
    // ---- S^T tiles: K frags read ONCE, used for both q-subtiles ----
#pragma unroll
    for (int t = 0; t < 4; ++t) {
      bf16x8 kf0 = *(const bf16x8*)&Kls[bb][(t * 16 + lc) * 64 + c0r * 8];
      bf16x8 kf1 = *(const bf16x8*)&Kls[bb][(t * 16 + lc) * 64 + c1r * 8];
#pragma unroll
      for (int s = 0; s < 2; ++s) {
        f32x4 z = {0.f, 0.f, 0.f, 0.f};
        z = __builtin_amdgcn_mfma_f32_16x16x32_bf16(kf0, qf[s][0], z, 0, 0, 0);
        z = __builtin_amdgcn_mfma_f32_16x16x32_bf16(kf1, qf[s][1], z, 0, 0, 0);
        float p0 = exp2f(z[0]);
        float p1 = exp2f(z[1]);
        float p2 = exp2f(z[2]);
        float p3 = exp2f(z[3]);
        rs[s] += (p0 + p1) + (p2 + p3);
        unsigned d0 = __builtin_amdgcn_perm(__float_as_uint(p1), __float_as_uint(p0), 0x07060302u);
        unsigned d1 = __builtin_amdgcn_perm(__float_as_uint(p3), __float_as_uint(p2), 0x07060302u);
        uint2 dd; dd.x = d0; dd.y = d1;
        *(uint2*)&P[w][s][lc * 72 + t * 16 + quad * 4] = dd;
      }
    }
    asm volatile("s_waitcnt lgkmcnt(0)" ::: "memory");
    bf16x8 pf[2][2];
#pragma unroll
    for (int s = 0; s < 2; ++s) {
      pf[s][0] = *(const bf16x8*)&P[w][s][lc * 72 + quad * 8];
      pf[s][1] = *(const bf16x8*)&P[w][s][lc * 72 + 32 + quad * 8];
    }
    // ---- O += P V : V frags read ONCE, used for both q-subtiles ----
#pragma unroll
    for (int dt = 0; dt < 4; ++dt) {
      bf16x8 vf0 = *(const bf16x8*)&Vls[bb][(dt * 16 + lc) * 64 + c0r * 8];
      bf16x8 vf1 = *(const bf16x8*)&Vls[bb][(dt * 16 + lc) * 64 + c1r * 8];
#pragma unroll
      for (int s = 0; s < 2; ++s) {
        o[s][dt] = __builtin_amdgcn_mfma_f32_16x16x32_bf16(pf[s][0], vf0, o[s][dt], 0, 0, 0);
        o[s][dt] = __builtin_amdgcn_mfma_f32_16x16x32_bf16(pf[s][1], vf1, o[s][dt], 0, 0, 0);
      }
    }
  }

  // finalize l per subtile: reduce per-lane partials across the 4 quads
  const int b = bh / CH, h = bh - b * CH;
#pragma unroll
  for (int s = 0; s < 2; ++s) {
    float r2 = rs[s];
    r2 += __shfl_xor(r2, 16, 64);
    r2 += __shfl_xor(r2, 32, 64);
#pragma unroll
    for (int r = 0; r < 4; ++r) {
      float lr = __shfl(r2, quad * 4 + r, 64);
      float inv = 1.0f / lr;
#pragma unroll
      for (int dt = 0; dt < 4; ++dt) {
        int i = b * CN + q0 + s * 16 + quad * 4 + r;
        int j = h * CDH + dt * 16 + lc;
        O[(size_t)i * CD + j] = f2bf(o[s][dt][r] * inv);
      }
    }
  }
}

extern "C" void kernel_launch(void* const* d_in, const int* in_sizes, int n_in,
                              void* d_out, int out_size, void* d_ws, size_t ws_size,
                              hipStream_t stream) {
  const float* x      = (const float*)d_in[0];
  const float* w_qkv  = (const float*)d_in[1];
  const float* b_qkv  = (const float*)d_in[2];
  const float* w_proj = (const float*)d_in[3];
  const float* b_proj = (const float*)d_in[4];
  float* out = (float*)d_out;
  unsigned short* ws = (unsigned short*)d_ws;

  unsigned short* xb      = ws;
  unsigned short* wqkv_t  = xb + (size_t)4096 * 768;
  unsigned short* wproj_t = wqkv_t + (size_t)2304 * 768;
  unsigned short* Qs  = wproj_t + (size_t)768 * 768;
  unsigned short* Ks  = Qs  + (size_t)CB * CH * CN * CDH;
  unsigned short* Vts = Ks  + (size_t)CB * CH * CN * CDH;
  unsigned short* AO  = Vts + (size_t)CB * CH * CN * CDH;

  const size_t smem_qkv  = (size_t)(128 * 136) * 2;      // Ct overlays As/Bs
  const size_t smem_proj = (size_t)(128 * 32 * 2) * 2;

  cvt8<<<(4096 * 768) / (256 * 8), 256, 0, stream>>>(x, xb);
  transpose_cvt<<<dim3(2304 / 64, 768 / 64), 256, 0, stream>>>(w_qkv, wqkv_t, 768, 2304);
  transpose_cvt<<<dim3(768 / 64, 768 / 64), 256, 0, stream>>>(w_proj, wproj_t, 768, 768);
  gemm128<<<dim3(2304 / 128, 4096 / 128), 256, smem_qkv, stream>>>(
      xb, wqkv_t, b_qkv, 4096, 2304, 768, 0, Qs, Ks, Vts, nullptr);
  attn64<<<dim3(CB * CH, CN / 128), 256, 0, stream>>>(Qs, Ks, Vts, AO);
  gemm128<<<dim3(768 / 128, 4096 / 128), 256, smem_proj, stream>>>(
      AO, wproj_t, b_proj, 4096, 768, 768, 1, nullptr, nullptr, nullptr, out);
}

// Round 7
// 192.242 us; speedup vs baseline: 1.0770x; 1.0770x over previous
//
#include <hip/hip_runtime.h>

// MultiHeadSelfAttention: B=2, N=2048, D=768, H=12, DH=64, scale=1/8.
// d_in / d_out are FP32; grading is bf16-leniency (2% of absmax).
// R7: attn reverted to R5 shape (4w x 16q, 768 blocks, 12 waves/CU) + Q
//     pre-scaled by log2(e)/8; prep kernels fused (6 -> 4 dispatches) to
//     test the ~15us/dispatch overhead theory. V^T coalesced epilogue kept.

#define CB 2
#define CN 2048
#define CD 768
#define CH 12
#define CDH 64
// exp(s/8) = exp2(s * 0.125 * log2(e)) ; folded into Q at QKV epilogue
#define CEXPSCALE 0.18033688f

typedef __bf16 bf16x8 __attribute__((ext_vector_type(8)));
typedef float f32x4 __attribute__((ext_vector_type(4)));
typedef unsigned short u16x8 __attribute__((ext_vector_type(8)));

static __device__ __forceinline__ unsigned short f2bf(float f) {
  union { float f; unsigned u; } v; v.f = f;
  unsigned r = v.u + 0x7fffu + ((v.u >> 16) & 1u);  // RNE
  return (unsigned short)(r >> 16);
}

// async global->LDS, 16B per lane; LDS dest = wave-uniform base + lane*16
static __device__ __forceinline__ void gld_lds16(const unsigned short* g, unsigned short* lds_base) {
  __builtin_amdgcn_global_load_lds(
      (const __attribute__((address_space(1))) unsigned int*)g,
      (__attribute__((address_space(3))) unsigned int*)(unsigned int)(unsigned long long)lds_base,
      16, 0, 0);
}

// ---------------- fused prep: cvt x -> bf16 AND transpose+cvt both weights ----
// grid 768 x 256. Each block: 2 chunks of x-cvt (block-partitioned), plus one
// 64x64 transpose tile if bid < 576 (432 w_qkv tiles + 144 w_proj tiles).
__global__ __launch_bounds__(256) void prep(const float* __restrict__ x,
                                            unsigned short* __restrict__ xb,
                                            const float* __restrict__ w_qkv,
                                            unsigned short* __restrict__ wqkv_t,
                                            const float* __restrict__ w_proj,
                                            unsigned short* __restrict__ wproj_t) {
  __shared__ __align__(16) unsigned short t[64][72];
  const int bid = blockIdx.x, tid = threadIdx.x;
  // ---- part 1: x conversion (4096 elems per block, 2 iters) ----
#pragma unroll
  for (int it = 0; it < 2; ++it) {
    size_t i = ((size_t)(bid * 2 + it) * 256 + tid) * 8;
    f32x4 a = *(const f32x4*)&x[i];
    f32x4 b = *(const f32x4*)&x[i + 4];
    u16x8 o;
#pragma unroll
    for (int j = 0; j < 4; ++j) { o[j] = f2bf(a[j]); o[4 + j] = f2bf(b[j]); }
    *(u16x8*)&xb[i] = o;
  }
  // ---- part 2: one weight transpose tile ----
  if (bid >= 576) return;
  const float* src; unsigned short* dst; int R, C, c0, r0;
  if (bid < 432) { src = w_qkv; dst = wqkv_t; R = 768; C = 2304; c0 = (bid % 36) * 64; r0 = (bid / 36) * 64; }
  else { int u = bid - 432; src = w_proj; dst = wproj_t; R = 768; C = 768; c0 = (u % 12) * 64; r0 = (u / 12) * 64; }
#pragma unroll
  for (int i = 0; i < 4; ++i) {
    int c = tid + i * 256;
    int row = c >> 4, cc = (c & 15) * 4;
    f32x4 v = *(const f32x4*)&src[(size_t)(r0 + row) * C + c0 + cc];
#pragma unroll
    for (int j = 0; j < 4; ++j) t[row][cc + j] = f2bf(v[j]);
  }
  __syncthreads();
#pragma unroll
  for (int i = 0; i < 2; ++i) {
    int c = tid + i * 256;
    int drow = c >> 3, rc = (c & 7) * 8;
    u16x8 v;
#pragma unroll
    for (int j = 0; j < 8; ++j) v[j] = t[rc + j][drow];
    *(u16x8*)&dst[(size_t)(c0 + drow) * R + r0 + rc] = v;
  }
}

// ---------------- GEMM: C[M,N] = A[M,K] @ Bt[N,K]^T + bias[N] ----------------
// Dynamic LDS: As(4096)|Bs(4096) elems; Ct (128x136) overlays them in the
// mode-0 V-block epilogue (after final barrier).
// mode 0: j<768 -> Q scatter (pre-scaled by CEXPSCALE); j<1536 -> K scatter;
//         col0>=1536 -> V^T via LDS transpose + coalesced b128 stores.
// mode 1: fp32 row-major store.
extern __shared__ __align__(16) unsigned short smem[];
__global__ __launch_bounds__(256) void gemm128(const unsigned short* __restrict__ A,
                                               const unsigned short* __restrict__ Bt,
                                               const float* __restrict__ bias,
                                               int M, int N, int K, int mode,
                                               unsigned short* __restrict__ o0,
                                               unsigned short* __restrict__ o1,
                                               unsigned short* __restrict__ o2,
                                               float* __restrict__ outF) {
  unsigned short* As = smem;
  unsigned short* Bs = smem + 128 * 32;
  unsigned short* Ct = smem;  // 128 x 136, overlays As/Bs in epilogue
  const int tid = threadIdx.x;
  const int w = tid >> 6, lane = tid & 63, quad = lane >> 4, lc = lane & 15;
  const int wm = (w >> 1) * 64, wn = (w & 1) * 64;
  const int row0 = blockIdx.y * 128, col0 = blockIdx.x * 128;
  f32x4 acc[4][4] = {};

  const int rl = lane >> 2, cl = lane & 3;
  const int gc = cl ^ ((rl >> 1) & 3);
  const int rsw = (lc >> 1) & 3;

  for (int k0 = 0; k0 < K; k0 += 32) {
#pragma unroll
    for (int j = 0; j < 2; ++j) {
      int r = w * 32 + j * 16 + rl;
      gld_lds16(&A[(size_t)(row0 + r) * K + k0 + gc * 8], &As[(w * 32 + j * 16) * 32]);
      gld_lds16(&Bt[(size_t)(col0 + r) * K + k0 + gc * 8], &Bs[(w * 32 + j * 16) * 32]);
    }
    __syncthreads();
    bf16x8 af[4], bfv[4];
#pragma unroll
    for (int mt = 0; mt < 4; ++mt)
      af[mt] = *(const bf16x8*)&As[(wm + mt * 16 + lc) * 32 + (quad ^ rsw) * 8];
#pragma unroll
    for (int nt = 0; nt < 4; ++nt)
      bfv[nt] = *(const bf16x8*)&Bs[(wn + nt * 16 + lc) * 32 + (quad ^ rsw) * 8];
#pragma unroll
    for (int mt = 0; mt < 4; ++mt)
#pragma unroll
      for (int nt = 0; nt < 4; ++nt)
        acc[mt][nt] = __builtin_amdgcn_mfma_f32_16x16x32_bf16(af[mt], bfv[nt], acc[mt][nt], 0, 0, 0);
    __syncthreads();
  }

  if (mode == 0 && col0 >= 1536) {
    // -------- V block: transpose through LDS, store V^T coalesced --------
#pragma unroll
    for (int mt = 0; mt < 4; ++mt) {
#pragma unroll
      for (int nt = 0; nt < 4; ++nt) {
        int jl = wn + nt * 16 + lc;            // V-dim (0..127)
        int il0 = wm + mt * 16 + quad * 4;     // token-dim, 4 consecutive
        float bj = bias[col0 + jl];
        unsigned short a0 = f2bf(acc[mt][nt][0] + bj);
        unsigned short a1 = f2bf(acc[mt][nt][1] + bj);
        unsigned short a2 = f2bf(acc[mt][nt][2] + bj);
        unsigned short a3 = f2bf(acc[mt][nt][3] + bj);
        uint2 dd;
        dd.x = (unsigned)a0 | ((unsigned)a1 << 16);
        dd.y = (unsigned)a2 | ((unsigned)a3 << 16);
        *(uint2*)&Ct[jl * 136 + il0] = dd;
      }
    }
    __syncthreads();
    const int b = row0 >> 11, n0 = row0 & 2047;
#pragma unroll
    for (int i = 0; i < 8; ++i) {
      int c = tid + i * 256;                   // 2048 chunks: 128 rows x 16
      int jl = c >> 4, cc = (c & 15) * 8;
      u16x8 v = *(const u16x8*)&Ct[jl * 136 + cc];
      int jcol = col0 - 1536 + jl;
      int h = jcol >> 6, d = jcol & 63;
      size_t gr = ((size_t)(b * CH + h) * CDH + d);
      *(u16x8*)&o2[gr * CN + n0 + cc] = v;
    }
  } else {
#pragma unroll
    for (int mt = 0; mt < 4; ++mt) {
#pragma unroll
      for (int nt = 0; nt < 4; ++nt) {
#pragma unroll
        for (int r = 0; r < 4; ++r) {
          int i = row0 + wm + mt * 16 + quad * 4 + r;
          int j = col0 + wn + nt * 16 + lc;
          float v = acc[mt][nt][r] + bias[j];
          if (mode == 0) {
            int b = i >> 11, n = i & 2047;
            int sec = (j >= 768) ? 1 : 0;      // col0>=1536 handled above
            int within = j - sec * 768;
            int h = within >> 6, d = within & 63;
            int bh = b * CH + h;
            if (sec == 0) o0[((size_t)bh * CN + n) * CDH + d] = f2bf(v * CEXPSCALE);
            else          o1[((size_t)bh * CN + n) * CDH + d] = f2bf(v);
          } else {
            outF[(size_t)i * N + j] = v;
          }
        }
      }
    }
  }
}

// ---------------- flash attention (R5 structure), no-max softmax -------------
// grid (B*H, N/64): bh pinned to one XCD (24%8==0). 4 waves x 16 q-rows,
// 768 blocks, 3 blocks/CU = 12 waves/CU (latency interleaving — the R6 lesson).
// K/V double-buffered via global_load_lds, XOR swizzle g = c ^ (row&7).
// Q arrives PRE-SCALED by log2(e)/8 -> p = exp2(z) directly.
__global__ __launch_bounds__(256, 3) void attn64(const unsigned short* __restrict__ Q,
                                                 const unsigned short* __restrict__ K,
                                                 const unsigned short* __restrict__ Vt,
                                                 unsigned short* __restrict__ O) {
  __shared__ __align__(16) unsigned short Kls[2][64 * 64];
  __shared__ __align__(16) unsigned short Vls[2][64 * 64];
  __shared__ __align__(16) unsigned short P[4][16][88];
  const int bh = blockIdx.x, qt = blockIdx.y;
  const int tid = threadIdx.x;
  const int w = tid >> 6, lane = tid & 63, quad = lane >> 4, lc = lane & 15;
  const unsigned short* Qb = Q + (size_t)bh * CN * CDH;
  const unsigned short* Kb = K + (size_t)bh * CN * CDH;
  const unsigned short* Vb = Vt + (size_t)bh * CDH * CN;
  const int q0 = qt * 64 + w * 16;

  const int sr = lane >> 3, sc = lane & 7;
  const int sg = sc ^ sr;
  const int ksw = lc & 7;
  const int c0r = quad ^ ksw;
  const int c1r = c0r ^ 4;

  bf16x8 qf0 = *(const bf16x8*)&Qb[(size_t)(q0 + lc) * CDH + quad * 8];
  bf16x8 qf1 = *(const bf16x8*)&Qb[(size_t)(q0 + lc) * CDH + 32 + quad * 8];

  f32x4 o[4] = {};
  float rs = 0.f;

#pragma unroll
  for (int j2 = 0; j2 < 2; ++j2) {
    int j = w * 2 + j2;
    int r = j * 8 + sr;
    gld_lds16(&Kb[(size_t)r * CDH + sg * 8], &Kls[0][j * 8 * 64]);
    gld_lds16(&Vb[(size_t)r * CN + 0 + sg * 8], &Vls[0][j * 8 * 64]);
  }

  for (int kt = 0; kt < CN / 64; ++kt) {
    const int bb = kt & 1;
    __syncthreads();  // tile kt staged
    if (kt + 1 < CN / 64) {
      const int kn = (kt + 1) * 64;
#pragma unroll
      for (int j2 = 0; j2 < 2; ++j2) {
        int j = w * 2 + j2;
        int r = j * 8 + sr;
        gld_lds16(&Kb[(size_t)(kn + r) * CDH + sg * 8], &Kls[bb ^ 1][j * 8 * 64]);
        gld_lds16(&Vb[(size_t)r * CN + kn + sg * 8], &Vls[bb ^ 1][j * 8 * 64]);
      }
    }
    // ---- S^T tiles: lane holds S^T[key=t*16+quad*4+r][qrow=lc] ----
#pragma unroll
    for (int t = 0; t < 4; ++t) {
      bf16x8 kf0 = *(const bf16x8*)&Kls[bb][(t * 16 + lc) * 64 + c0r * 8];
      bf16x8 kf1 = *(const bf16x8*)&Kls[bb][(t * 16 + lc) * 64 + c1r * 8];
      f32x4 z = {0.f, 0.f, 0.f, 0.f};
      z = __builtin_amdgcn_mfma_f32_16x16x32_bf16(kf0, qf0, z, 0, 0, 0);
      z = __builtin_amdgcn_mfma_f32_16x16x32_bf16(kf1, qf1, z, 0, 0, 0);
      float p0 = exp2f(z[0]);
      float p1 = exp2f(z[1]);
      float p2 = exp2f(z[2]);
      float p3 = exp2f(z[3]);
      rs += (p0 + p1) + (p2 + p3);
      unsigned d0 = __builtin_amdgcn_perm(__float_as_uint(p1), __float_as_uint(p0), 0x07060302u);
      unsigned d1 = __builtin_amdgcn_perm(__float_as_uint(p3), __float_as_uint(p2), 0x07060302u);
      uint2 dd; dd.x = d0; dd.y = d1;
      *(uint2*)&P[w][lc][t * 16 + quad * 4] = dd;
    }
    asm volatile("s_waitcnt lgkmcnt(0)" ::: "memory");
    bf16x8 pf0 = *(const bf16x8*)&P[w][lc][quad * 8];
    bf16x8 pf1 = *(const bf16x8*)&P[w][lc][32 + quad * 8];
#pragma unroll
    for (int dt = 0; dt < 4; ++dt) {
      bf16x8 vf0 = *(const bf16x8*)&Vls[bb][(dt * 16 + lc) * 64 + c0r * 8];
      bf16x8 vf1 = *(const bf16x8*)&Vls[bb][(dt * 16 + lc) * 64 + c1r * 8];
      o[dt] = __builtin_amdgcn_mfma_f32_16x16x32_bf16(pf0, vf0, o[dt], 0, 0, 0);
      o[dt] = __builtin_amdgcn_mfma_f32_16x16x32_bf16(pf1, vf1, o[dt], 0, 0, 0);
    }
  }

  rs += __shfl_xor(rs, 16, 64);
  rs += __shfl_xor(rs, 32, 64);
  const int b = bh / CH, h = bh - b * CH;
#pragma unroll
  for (int r = 0; r < 4; ++r) {
    float lr = __shfl(rs, quad * 4 + r, 64);
    float inv = 1.0f / lr;
#pragma unroll
    for (int dt = 0; dt < 4; ++dt) {
      int i = b * CN + q0 + quad * 4 + r;
      int j = h * CDH + dt * 16 + lc;
      O[(size_t)i * CD + j] = f2bf(o[dt][r] * inv);
    }
  }
}

extern "C" void kernel_launch(void* const* d_in, const int* in_sizes, int n_in,
                              void* d_out, int out_size, void* d_ws, size_t ws_size,
                              hipStream_t stream) {
  const float* x      = (const float*)d_in[0];
  const float* w_qkv  = (const float*)d_in[1];
  const float* b_qkv  = (const float*)d_in[2];
  const float* w_proj = (const float*)d_in[3];
  const float* b_proj = (const float*)d_in[4];
  float* out = (float*)d_out;
  unsigned short* ws = (unsigned short*)d_ws;

  unsigned short* xb      = ws;
  unsigned short* wqkv_t  = xb + (size_t)4096 * 768;
  unsigned short* wproj_t = wqkv_t + (size_t)2304 * 768;
  unsigned short* Qs  = wproj_t + (size_t)768 * 768;
  unsigned short* Ks  = Qs  + (size_t)CB * CH * CN * CDH;
  unsigned short* Vts = Ks  + (size_t)CB * CH * CN * CDH;
  unsigned short* AO  = Vts + (size_t)CB * CH * CN * CDH;

  const size_t smem_qkv  = (size_t)(128 * 136) * 2;  // Ct overlays As/Bs
  const size_t smem_proj = (size_t)(128 * 32 * 2) * 2;

  prep<<<768, 256, 0, stream>>>(x, xb, w_qkv, wqkv_t, w_proj, wproj_t);
  gemm128<<<dim3(2304 / 128, 4096 / 128), 256, smem_qkv, stream>>>(
      xb, wqkv_t, b_qkv, 4096, 2304, 768, 0, Qs, Ks, Vts, nullptr);
  attn64<<<dim3(CB * CH, CN / 64), 256, 0, stream>>>(Qs, Ks, Vts, AO);
  gemm128<<<dim3(768 / 128, 4096 / 128), 256, smem_proj, stream>>>(
      AO, wproj_t, b_proj, 4096, 768, 768, 1, nullptr, nullptr, nullptr, out);
}

// Round 8
// 169.571 us; speedup vs baseline: 1.2210x; 1.1337x over previous
//
#include <hip/hip_runtime.h>

// MultiHeadSelfAttention: B=2, N=2048, D=768, H=12, DH=64, scale=1/8.
// d_in / d_out are FP32; grading is bf16-leniency (2% of absmax).
// R8: GEMMs rebuilt as gemm_db<TM,TN> — LDS double-buffered k-loop (ONE
//     barrier per k-step; prefetch kt+1 issued right after the barrier,
//     computing kt from the other buffer), occupancy-first tiles:
//     QKV <64,128> = 1152 blocks (4.5/CU), proj <64,64> = 768 blocks (3/CU).
//     attn64 unchanged from R7 (57.9 us measured).

#define CB 2
#define CN 2048
#define CD 768
#define CH 12
#define CDH 64
// exp(s/8) = exp2(s * 0.125 * log2(e)) ; folded into Q at QKV epilogue
#define CEXPSCALE 0.18033688f

typedef __bf16 bf16x8 __attribute__((ext_vector_type(8)));
typedef float f32x4 __attribute__((ext_vector_type(4)));
typedef unsigned short u16x8 __attribute__((ext_vector_type(8)));

static __device__ __forceinline__ unsigned short f2bf(float f) {
  union { float f; unsigned u; } v; v.f = f;
  unsigned r = v.u + 0x7fffu + ((v.u >> 16) & 1u);  // RNE
  return (unsigned short)(r >> 16);
}

// async global->LDS, 16B per lane; LDS dest = wave-uniform base + lane*16
static __device__ __forceinline__ void gld_lds16(const unsigned short* g, unsigned short* lds_base) {
  __builtin_amdgcn_global_load_lds(
      (const __attribute__((address_space(1))) unsigned int*)g,
      (__attribute__((address_space(3))) unsigned int*)(unsigned int)(unsigned long long)lds_base,
      16, 0, 0);
}

// ---------------- fused prep: cvt x -> bf16 AND transpose+cvt both weights ----
__global__ __launch_bounds__(256) void prep(const float* __restrict__ x,
                                            unsigned short* __restrict__ xb,
                                            const float* __restrict__ w_qkv,
                                            unsigned short* __restrict__ wqkv_t,
                                            const float* __restrict__ w_proj,
                                            unsigned short* __restrict__ wproj_t) {
  __shared__ __align__(16) unsigned short t[64][72];
  const int bid = blockIdx.x, tid = threadIdx.x;
#pragma unroll
  for (int it = 0; it < 2; ++it) {
    size_t i = ((size_t)(bid * 2 + it) * 256 + tid) * 8;
    f32x4 a = *(const f32x4*)&x[i];
    f32x4 b = *(const f32x4*)&x[i + 4];
    u16x8 o;
#pragma unroll
    for (int j = 0; j < 4; ++j) { o[j] = f2bf(a[j]); o[4 + j] = f2bf(b[j]); }
    *(u16x8*)&xb[i] = o;
  }
  if (bid >= 576) return;
  const float* src; unsigned short* dst; int R, C, c0, r0;
  if (bid < 432) { src = w_qkv; dst = wqkv_t; R = 768; C = 2304; c0 = (bid % 36) * 64; r0 = (bid / 36) * 64; }
  else { int u = bid - 432; src = w_proj; dst = wproj_t; R = 768; C = 768; c0 = (u % 12) * 64; r0 = (u / 12) * 64; }
#pragma unroll
  for (int i = 0; i < 4; ++i) {
    int c = tid + i * 256;
    int row = c >> 4, cc = (c & 15) * 4;
    f32x4 v = *(const f32x4*)&src[(size_t)(r0 + row) * C + c0 + cc];
#pragma unroll
    for (int j = 0; j < 4; ++j) t[row][cc + j] = f2bf(v[j]);
  }
  __syncthreads();
#pragma unroll
  for (int i = 0; i < 2; ++i) {
    int c = tid + i * 256;
    int drow = c >> 3, rc = (c & 7) * 8;
    u16x8 v;
#pragma unroll
    for (int j = 0; j < 8; ++j) v[j] = t[rc + j][drow];
    *(u16x8*)&dst[(size_t)(c0 + drow) * R + r0 + rc] = v;
  }
}

// ---------------- GEMM, double-buffered: C[M,N] = A @ Bt^T + bias ------------
// TM x TN tile, 4 waves (each 32 x TN/2). One __syncthreads per k-step:
//   barrier -> stage(kt+1, other buf) -> compute(kt).
// Drain at the NEXT barrier waits on DMA issued a full compute-phase earlier.
// mode 0 (QKV): j<768 Q scatter (pre-scaled by CEXPSCALE); j<1536 K scatter;
//               col0>=1536 V^T via LDS-transpose (Ct overlays dbuf LDS).
// mode 1: fp32 row-major store.
extern __shared__ __align__(16) unsigned short smem[];

template <int TM, int TN>
__global__ __launch_bounds__(256, 4) void gemm_db(const unsigned short* __restrict__ A,
                                                  const unsigned short* __restrict__ Bt,
                                                  const float* __restrict__ bias,
                                                  int M, int N, int K, int mode,
                                                  unsigned short* __restrict__ o0,
                                                  unsigned short* __restrict__ o1,
                                                  unsigned short* __restrict__ o2,
                                                  float* __restrict__ outF) {
  constexpr int NT = TN / 32;                 // n-subtiles per wave
  unsigned short* As = smem;                  // [2][TM*32]
  unsigned short* Bs = smem + 2 * TM * 32;    // [2][TN*32]
  unsigned short* Ct = smem;                  // TN x (TM+8) overlay (epilogue)
  const int tid = threadIdx.x;
  const int w = tid >> 6, lane = tid & 63, quad = lane >> 4, lc = lane & 15;
  const int wm = (w >> 1) * 32, wn = (w & 1) * (TN / 2);
  const int row0 = blockIdx.y * TM, col0 = blockIdx.x * TN;
  f32x4 acc[2][NT] = {};

  const int rl = lane >> 2, cl = lane & 3;
  const int gc = cl ^ ((rl >> 1) & 3);        // store-side XOR chunk swizzle
  const int rsw = (lc >> 1) & 3;              // read-side unswizzle
  const int nk = K / 32;

  auto stage = [&](int kt, int buf) {
    const int k0 = kt * 32;
    // A: wave w stages rows [w*16, w*16+16)
    gld_lds16(&A[(size_t)(row0 + w * 16 + rl) * K + k0 + gc * 8],
              &As[buf * (TM * 32) + (w * 16) * 32]);
    // B: wave w stages rows [w*(TN/4), +TN/4)
#pragma unroll
    for (int jb = 0; jb < TN / 64; ++jb)
      gld_lds16(&Bt[(size_t)(col0 + w * (TN / 4) + jb * 16 + rl) * K + k0 + gc * 8],
                &Bs[buf * (TN * 32) + (w * (TN / 4) + jb * 16) * 32]);
  };

  stage(0, 0);
  for (int kt = 0; kt < nk; ++kt) {
    const int bb = kt & 1;
    __syncthreads();                          // buf bb staged; prior reads done
    if (kt + 1 < nk) stage(kt + 1, bb ^ 1);
    bf16x8 af[2], bfv[NT];
#pragma unroll
    for (int mt = 0; mt < 2; ++mt)
      af[mt] = *(const bf16x8*)&As[bb * (TM * 32) + (wm + mt * 16 + lc) * 32 + (quad ^ rsw) * 8];
#pragma unroll
    for (int nt = 0; nt < NT; ++nt)
      bfv[nt] = *(const bf16x8*)&Bs[bb * (TN * 32) + (wn + nt * 16 + lc) * 32 + (quad ^ rsw) * 8];
#pragma unroll
    for (int mt = 0; mt < 2; ++mt)
#pragma unroll
      for (int nt = 0; nt < NT; ++nt)
        acc[mt][nt] = __builtin_amdgcn_mfma_f32_16x16x32_bf16(af[mt], bfv[nt], acc[mt][nt], 0, 0, 0);
  }

  if (mode == 0 && col0 >= 1536) {
    // -------- V block: transpose through LDS, store V^T coalesced --------
    __syncthreads();                          // last compute reads done
#pragma unroll
    for (int mt = 0; mt < 2; ++mt) {
#pragma unroll
      for (int nt = 0; nt < NT; ++nt) {
        int jl = wn + nt * 16 + lc;           // V-dim (0..TN)
        int il0 = wm + mt * 16 + quad * 4;    // token-dim, 4 consecutive
        float bj = bias[col0 + jl];
        unsigned short a0 = f2bf(acc[mt][nt][0] + bj);
        unsigned short a1 = f2bf(acc[mt][nt][1] + bj);
        unsigned short a2 = f2bf(acc[mt][nt][2] + bj);
        unsigned short a3 = f2bf(acc[mt][nt][3] + bj);
        uint2 dd;
        dd.x = (unsigned)a0 | ((unsigned)a1 << 16);
        dd.y = (unsigned)a2 | ((unsigned)a3 << 16);
        *(uint2*)&Ct[jl * (TM + 8) + il0] = dd;
      }
    }
    __syncthreads();
    const int b = row0 >> 11, n0 = row0 & 2047;
    constexpr int CPR = TM / 8;               // 8-elem chunks per Ct row
#pragma unroll
    for (int i = 0; i < (TN * CPR) / 256; ++i) {
      int c = tid + i * 256;
      int jl = c / CPR, cc = (c % CPR) * 8;
      u16x8 v = *(const u16x8*)&Ct[jl * (TM + 8) + cc];
      int jcol = col0 - 1536 + jl;
      int h = jcol >> 6, d = jcol & 63;
      size_t gr = ((size_t)(b * CH + h) * CDH + d);
      *(u16x8*)&o2[gr * CN + n0 + cc] = v;
    }
  } else {
#pragma unroll
    for (int mt = 0; mt < 2; ++mt) {
#pragma unroll
      for (int nt = 0; nt < NT; ++nt) {
#pragma unroll
        for (int r = 0; r < 4; ++r) {
          int i = row0 + wm + mt * 16 + quad * 4 + r;
          int j = col0 + wn + nt * 16 + lc;
          float v = acc[mt][nt][r] + bias[j];
          if (mode == 0) {
            int b = i >> 11, n = i & 2047;
            int sec = (j >= 768) ? 1 : 0;     // V handled above
            int within = j - sec * 768;
            int h = within >> 6, d = within & 63;
            int bh = b * CH + h;
            if (sec == 0) o0[((size_t)bh * CN + n) * CDH + d] = f2bf(v * CEXPSCALE);
            else          o1[((size_t)bh * CN + n) * CDH + d] = f2bf(v);
          } else {
            outF[(size_t)i * N + j] = v;
          }
        }
      }
    }
  }
}

// ---------------- flash attention (R7, measured 57.9us), no-max softmax ------
__global__ __launch_bounds__(256, 3) void attn64(const unsigned short* __restrict__ Q,
                                                 const unsigned short* __restrict__ K,
                                                 const unsigned short* __restrict__ Vt,
                                                 unsigned short* __restrict__ O) {
  __shared__ __align__(16) unsigned short Kls[2][64 * 64];
  __shared__ __align__(16) unsigned short Vls[2][64 * 64];
  __shared__ __align__(16) unsigned short P[4][16][88];
  const int bh = blockIdx.x, qt = blockIdx.y;
  const int tid = threadIdx.x;
  const int w = tid >> 6, lane = tid & 63, quad = lane >> 4, lc = lane & 15;
  const unsigned short* Qb = Q + (size_t)bh * CN * CDH;
  const unsigned short* Kb = K + (size_t)bh * CN * CDH;
  const unsigned short* Vb = Vt + (size_t)bh * CDH * CN;
  const int q0 = qt * 64 + w * 16;

  const int sr = lane >> 3, sc = lane & 7;
  const int sg = sc ^ sr;
  const int ksw = lc & 7;
  const int c0r = quad ^ ksw;
  const int c1r = c0r ^ 4;

  bf16x8 qf0 = *(const bf16x8*)&Qb[(size_t)(q0 + lc) * CDH + quad * 8];
  bf16x8 qf1 = *(const bf16x8*)&Qb[(size_t)(q0 + lc) * CDH + 32 + quad * 8];

  f32x4 o[4] = {};
  float rs = 0.f;

#pragma unroll
  for (int j2 = 0; j2 < 2; ++j2) {
    int j = w * 2 + j2;
    int r = j * 8 + sr;
    gld_lds16(&Kb[(size_t)r * CDH + sg * 8], &Kls[0][j * 8 * 64]);
    gld_lds16(&Vb[(size_t)r * CN + 0 + sg * 8], &Vls[0][j * 8 * 64]);
  }

  for (int kt = 0; kt < CN / 64; ++kt) {
    const int bb = kt & 1;
    __syncthreads();
    if (kt + 1 < CN / 64) {
      const int kn = (kt + 1) * 64;
#pragma unroll
      for (int j2 = 0; j2 < 2; ++j2) {
        int j = w * 2 + j2;
        int r = j * 8 + sr;
        gld_lds16(&Kb[(size_t)(kn + r) * CDH + sg * 8], &Kls[bb ^ 1][j * 8 * 64]);
        gld_lds16(&Vb[(size_t)r * CN + kn + sg * 8], &Vls[bb ^ 1][j * 8 * 64]);
      }
    }
#pragma unroll
    for (int t = 0; t < 4; ++t) {
      bf16x8 kf0 = *(const bf16x8*)&Kls[bb][(t * 16 + lc) * 64 + c0r * 8];
      bf16x8 kf1 = *(const bf16x8*)&Kls[bb][(t * 16 + lc) * 64 + c1r * 8];
      f32x4 z = {0.f, 0.f, 0.f, 0.f};
      z = __builtin_amdgcn_mfma_f32_16x16x32_bf16(kf0, qf0, z, 0, 0, 0);
      z = __builtin_amdgcn_mfma_f32_16x16x32_bf16(kf1, qf1, z, 0, 0, 0);
      float p0 = exp2f(z[0]);
      float p1 = exp2f(z[1]);
      float p2 = exp2f(z[2]);
      float p3 = exp2f(z[3]);
      rs += (p0 + p1) + (p2 + p3);
      unsigned d0 = __builtin_amdgcn_perm(__float_as_uint(p1), __float_as_uint(p0), 0x07060302u);
      unsigned d1 = __builtin_amdgcn_perm(__float_as_uint(p3), __float_as_uint(p2), 0x07060302u);
      uint2 dd; dd.x = d0; dd.y = d1;
      *(uint2*)&P[w][lc][t * 16 + quad * 4] = dd;
    }
    asm volatile("s_waitcnt lgkmcnt(0)" ::: "memory");
    bf16x8 pf0 = *(const bf16x8*)&P[w][lc][quad * 8];
    bf16x8 pf1 = *(const bf16x8*)&P[w][lc][32 + quad * 8];
#pragma unroll
    for (int dt = 0; dt < 4; ++dt) {
      bf16x8 vf0 = *(const bf16x8*)&Vls[bb][(dt * 16 + lc) * 64 + c0r * 8];
      bf16x8 vf1 = *(const bf16x8*)&Vls[bb][(dt * 16 + lc) * 64 + c1r * 8];
      o[dt] = __builtin_amdgcn_mfma_f32_16x16x32_bf16(pf0, vf0, o[dt], 0, 0, 0);
      o[dt] = __builtin_amdgcn_mfma_f32_16x16x32_bf16(pf1, vf1, o[dt], 0, 0, 0);
    }
  }

  rs += __shfl_xor(rs, 16, 64);
  rs += __shfl_xor(rs, 32, 64);
  const int b = bh / CH, h = bh - b * CH;
#pragma unroll
  for (int r = 0; r < 4; ++r) {
    float lr = __shfl(rs, quad * 4 + r, 64);
    float inv = 1.0f / lr;
#pragma unroll
    for (int dt = 0; dt < 4; ++dt) {
      int i = b * CN + q0 + quad * 4 + r;
      int j = h * CDH + dt * 16 + lc;
      O[(size_t)i * CD + j] = f2bf(o[dt][r] * inv);
    }
  }
}

extern "C" void kernel_launch(void* const* d_in, const int* in_sizes, int n_in,
                              void* d_out, int out_size, void* d_ws, size_t ws_size,
                              hipStream_t stream) {
  const float* x      = (const float*)d_in[0];
  const float* w_qkv  = (const float*)d_in[1];
  const float* b_qkv  = (const float*)d_in[2];
  const float* w_proj = (const float*)d_in[3];
  const float* b_proj = (const float*)d_in[4];
  float* out = (float*)d_out;
  unsigned short* ws = (unsigned short*)d_ws;

  unsigned short* xb      = ws;
  unsigned short* wqkv_t  = xb + (size_t)4096 * 768;
  unsigned short* wproj_t = wqkv_t + (size_t)2304 * 768;
  unsigned short* Qs  = wproj_t + (size_t)768 * 768;
  unsigned short* Ks  = Qs  + (size_t)CB * CH * CN * CDH;
  unsigned short* Vts = Ks  + (size_t)CB * CH * CN * CDH;
  unsigned short* AO  = Vts + (size_t)CB * CH * CN * CDH;

  // dbuf LDS: 2*(TM+TN)*32 bf16 elems; Ct overlay fits inside
  const size_t smem_qkv  = (size_t)2 * (64 + 128) * 32 * 2;  // 24576 B
  const size_t smem_proj = (size_t)2 * (64 + 64) * 32 * 2;   // 16384 B

  prep<<<768, 256, 0, stream>>>(x, xb, w_qkv, wqkv_t, w_proj, wproj_t);
  gemm_db<64, 128><<<dim3(2304 / 128, 4096 / 64), 256, smem_qkv, stream>>>(
      xb, wqkv_t, b_qkv, 4096, 2304, 768, 0, Qs, Ks, Vts, nullptr);
  attn64<<<dim3(CB * CH, CN / 64), 256, 0, stream>>>(Qs, Ks, Vts, AO);
  gemm_db<64, 64><<<dim3(768 / 64, 4096 / 64), 256, smem_proj, stream>>>(
      AO, wproj_t, b_proj, 4096, 768, 768, 1, nullptr, nullptr, nullptr, out);
}